// Round 10
// baseline (576.249 us; speedup 1.0000x reference)
//
#include <hip/hip_runtime.h>
#include <hip/hip_bf16.h>

#define M_CH 2
#define J_F 2000
#define I_F 2049
#define K_B 8
#define N_IT 5
#define NMF_EPS 1e-20f
#define IP_EPS 1e-20f

// bijective XCD swizzle for NB blocks over 8 XCDs (m204 formula)
template<int NB>
__device__ __forceinline__ int swz(int orig) {
  constexpr int q = NB / 8, r = NB % 8;
  int xcd = orig & 7, rest = orig >> 3;
  return (xcd < r ? xcd * (q + 1) : r * (q + 1) + (xcd - r) * q) + rest;
}

// ---------------- init: T[n][i][k], V[n][k][j], W[i] = eye ----------------
__global__ void k_init(const float* __restrict__ T0, const float* __restrict__ V0,
                       float* __restrict__ T, float* __restrict__ V, float* __restrict__ W) {
  int t = blockIdx.x * blockDim.x + threadIdx.x;
  int stride = gridDim.x * blockDim.x;
  for (int idx = t; idx < 2 * I_F * K_B; idx += stride) {
    int n = idx / (I_F * K_B);
    int r = idx % (I_F * K_B);
    int i = r / K_B, k = r % K_B;
    T[idx] = T0[(i * K_B + k) * M_CH + n];
  }
  for (int idx = t; idx < 2 * K_B * J_F; idx += stride) {
    int n = idx / (K_B * J_F);
    int r = idx % (K_B * J_F);
    int k = r / J_F, j = r % J_F;
    V[idx] = V0[(k * J_F + j) * M_CH + n];
  }
  for (int i = t; i < I_F; i += stride) {
    W[i * 8 + 0] = 1.f; W[i * 8 + 1] = 0.f; W[i * 8 + 2] = 0.f; W[i * 8 + 3] = 0.f;
    W[i * 8 + 4] = 0.f; W[i * 8 + 5] = 0.f; W[i * 8 + 6] = 1.f; W[i * 8 + 7] = 0.f;
  }
}

// ------------- pack X: Xp[j][i] = (x0r,x0i,x1r,x1i) -------------
__global__ __launch_bounds__(256) void k_pack(const float2* __restrict__ X,
                                              float4* __restrict__ Xp) {
  const int i = blockIdx.x * 256 + threadIdx.x;
  if (i >= I_F) return;
  const int j0 = blockIdx.y * 8;
  const int jend = min(8, J_F - j0);
  for (int jj = 0; jj < jend; ++jj) {
    const int j = j0 + jj;
    float2 a = X[(size_t)j * I_F + i];
    float2 b = X[(size_t)(J_F + j) * I_F + i];
    Xp[(size_t)j * I_F + i] = make_float4(a.x, a.y, b.x, b.y);
  }
}

__device__ __forceinline__ float4 load_x(const float4* Xp, const float2* X,
                                         int pk, size_t j, int i) {
  if (pk) return Xp[j * I_F + i];
  float2 a = X[j * I_F + i];
  float2 b = X[(size_t)J_F * I_F + j * I_F + i];
  return make_float4(a.x, a.y, b.x, b.y);
}

// ---- T-update partials, BOTH n per thread ----
template<int PK, int TILES>
__global__ __launch_bounds__(256) void k_T_partial(const float4* __restrict__ Xp,
                                                   const float2* __restrict__ X,
                                                   const float* __restrict__ W,
                                                   const float* __restrict__ T,
                                                   const float* __restrict__ V,
                                                   float* __restrict__ Tpart) {
  constexpr int TSZ = J_F / TILES;
  const int w = swz<9 * TILES>(blockIdx.x);
  const int yb = w / 9, xb = w % 9;
  __shared__ float Vl[2][K_B][TSZ];
  const int tid = threadIdx.x;
  const int j0 = yb * TSZ;
  for (int idx = tid; idx < 2 * K_B * TSZ; idx += 256) {
    int n = idx / (K_B * TSZ);
    int rr = idx % (K_B * TSZ);
    int k = rr / TSZ, jj = rr % TSZ;
    Vl[n][k][jj] = V[((size_t)n * K_B + k) * J_F + j0 + jj];
  }
  __syncthreads();
  const int i = xb * 256 + tid;
  if (i >= I_F) return;
  float tr0[K_B], tr1[K_B];
#pragma unroll
  for (int k = 0; k < K_B; ++k) {
    tr0[k] = T[(size_t)i * 8 + k];
    tr1[k] = T[((size_t)I_F + i) * 8 + k];
  }
  const float4 w0 = ((const float4*)W)[i * 2];
  const float4 w1 = ((const float4*)W)[i * 2 + 1];
  float num0[K_B] = {}, den0[K_B] = {}, num1[K_B] = {}, den1[K_B] = {};
#pragma unroll 2
  for (int jj = 0; jj < TSZ; ++jj) {
    float4 x = load_x(Xp, X, PK, (size_t)(j0 + jj), i);
    float yr = w0.x * x.x - w0.y * x.y + w0.z * x.z - w0.w * x.w;
    float yi = w0.x * x.y + w0.y * x.x + w0.z * x.w + w0.w * x.z;
    float p0 = yr * yr + yi * yi;
    float zr = w1.x * x.x - w1.y * x.y + w1.z * x.z - w1.w * x.w;
    float zi = w1.x * x.y + w1.y * x.x + w1.z * x.w + w1.w * x.z;
    float p1 = zr * zr + zi * zi;
    float R0 = 0.f, R1 = 0.f;
#pragma unroll
    for (int k = 0; k < K_B; ++k) {
      R0 += tr0[k] * Vl[0][k][jj];
      R1 += tr1[k] * Vl[1][k][jj];
    }
    float a0 = p0 / (R0 * R0), b0 = 1.0f / R0;
    float a1 = p1 / (R1 * R1), b1 = 1.0f / R1;
#pragma unroll
    for (int k = 0; k < K_B; ++k) {
      num0[k] += a0 * Vl[0][k][jj]; den0[k] += b0 * Vl[0][k][jj];
      num1[k] += a1 * Vl[1][k][jj]; den1[k] += b1 * Vl[1][k][jj];
    }
  }
  float* b0_ = Tpart + (((size_t)0 * TILES + yb) * I_F + i) * 16;
  float* b1_ = Tpart + (((size_t)1 * TILES + yb) * I_F + i) * 16;
  *(float4*)(b0_ + 0)  = make_float4(num0[0], num0[1], num0[2], num0[3]);
  *(float4*)(b0_ + 4)  = make_float4(num0[4], num0[5], num0[6], num0[7]);
  *(float4*)(b0_ + 8)  = make_float4(den0[0], den0[1], den0[2], den0[3]);
  *(float4*)(b0_ + 12) = make_float4(den0[4], den0[5], den0[6], den0[7]);
  *(float4*)(b1_ + 0)  = make_float4(num1[0], num1[1], num1[2], num1[3]);
  *(float4*)(b1_ + 4)  = make_float4(num1[4], num1[5], num1[6], num1[7]);
  *(float4*)(b1_ + 8)  = make_float4(den1[0], den1[1], den1[2], den1[3]);
  *(float4*)(b1_ + 12) = make_float4(den1[4], den1[5], den1[6], den1[7]);
}

// ------- finish T: 4 lanes per (n,i,k), quad shfl reduce -------
template<int TILES>
__global__ __launch_bounds__(256) void k_t_finish(const float* __restrict__ Tpart,
                                                  float* __restrict__ T) {
  int g = blockIdx.x * 256 + threadIdx.x;
  int e = g >> 2, part = g & 3;
  if (e >= 2 * I_F * K_B) return;
  int n = e / (I_F * K_B);
  int r = e % (I_F * K_B);
  int i = r >> 3, k = r & 7;
  const size_t S = (size_t)I_F * 16;
  const float* p = Tpart + ((size_t)n * TILES) * S + (size_t)i * 16;
  constexpr int per = TILES / 4;
  int jt = part * per;
  const int jend = jt + per;
  float n0 = 0.f, n1 = 0.f, d0 = 0.f, d1 = 0.f;
  for (; jt + 1 < jend; jt += 2) {
    n0 += p[(size_t)jt * S + k];         d0 += p[(size_t)jt * S + 8 + k];
    n1 += p[(size_t)(jt + 1) * S + k];   d1 += p[(size_t)(jt + 1) * S + 8 + k];
  }
  if (jt < jend) { n0 += p[(size_t)jt * S + k]; d0 += p[(size_t)jt * S + 8 + k]; }
  float num = n0 + n1, den = d0 + d1;
  num += __shfl_xor(num, 1, 64); den += __shfl_xor(den, 1, 64);
  num += __shfl_xor(num, 2, 64); den += __shfl_xor(den, 2, 64);
  if (part == 0) {
    float told = T[e];
    T[e] = fmaxf(told * sqrtf(num / den), NMF_EPS);
  }
}

// -- V update: block per j, both n, recompute P from Xp, full i-reduce, in place --
template<int PK>
__global__ __launch_bounds__(256) void k_v_update(const float4* __restrict__ Xp,
                                                  const float2* __restrict__ X,
                                                  const float* __restrict__ W,
                                                  const float* __restrict__ T,
                                                  float* __restrict__ V) {
  const int j = blockIdx.x;
  const int tid = threadIdx.x;
  float vold0[K_B], vold1[K_B];
#pragma unroll
  for (int k = 0; k < K_B; ++k) {
    vold0[k] = V[(size_t)k * J_F + j];
    vold1[k] = V[(size_t)(K_B + k) * J_F + j];
  }
  float num0[K_B] = {}, den0[K_B] = {}, num1[K_B] = {}, den1[K_B] = {};
  const float* T1 = T + (size_t)I_F * K_B;
  for (int i = tid; i < I_F; i += 256) {
    float4 x = load_x(Xp, X, PK, (size_t)j, i);
    const float4 wa = ((const float4*)W)[i * 2];
    const float4 wb = ((const float4*)W)[i * 2 + 1];
    float yr = wa.x * x.x - wa.y * x.y + wa.z * x.z - wa.w * x.w;
    float yi = wa.x * x.y + wa.y * x.x + wa.z * x.w + wa.w * x.z;
    float p0 = yr * yr + yi * yi;
    float zr = wb.x * x.x - wb.y * x.y + wb.z * x.z - wb.w * x.w;
    float zi = wb.x * x.y + wb.y * x.x + wb.z * x.w + wb.w * x.z;
    float p1 = zr * zr + zi * zi;
    const float4 ta = *(const float4*)&T[i * 8];
    const float4 tb = *(const float4*)&T[i * 8 + 4];
    const float4 tc = *(const float4*)&T1[i * 8];
    const float4 td = *(const float4*)&T1[i * 8 + 4];
    float t0[K_B] = {ta.x, ta.y, ta.z, ta.w, tb.x, tb.y, tb.z, tb.w};
    float t1[K_B] = {tc.x, tc.y, tc.z, tc.w, td.x, td.y, td.z, td.w};
    float R0 = 0.f, R1 = 0.f;
#pragma unroll
    for (int k = 0; k < K_B; ++k) { R0 += t0[k] * vold0[k]; R1 += t1[k] * vold1[k]; }
    float a0 = p0 / (R0 * R0), b0 = 1.0f / R0;
    float a1 = p1 / (R1 * R1), b1 = 1.0f / R1;
#pragma unroll
    for (int k = 0; k < K_B; ++k) {
      num0[k] += a0 * t0[k]; den0[k] += b0 * t0[k];
      num1[k] += a1 * t1[k]; den1[k] += b1 * t1[k];
    }
  }
  __shared__ float red[4][32];
  const int lane = tid & 63, wid = tid >> 6;
#pragma unroll
  for (int k = 0; k < K_B; ++k) {
    float a0 = num0[k], b0 = den0[k], a1 = num1[k], b1 = den1[k];
#pragma unroll
    for (int off = 32; off > 0; off >>= 1) {
      a0 += __shfl_xor(a0, off, 64);
      b0 += __shfl_xor(b0, off, 64);
      a1 += __shfl_xor(a1, off, 64);
      b1 += __shfl_xor(b1, off, 64);
    }
    if (lane == 0) {
      red[wid][k] = a0; red[wid][8 + k] = b0;
      red[wid][16 + k] = a1; red[wid][24 + k] = b1;
    }
  }
  __syncthreads();
  if (tid < 32) red[0][tid] = red[0][tid] + red[1][tid] + red[2][tid] + red[3][tid];
  __syncthreads();
  if (tid < 16) {
    int n = tid >> 3, k = tid & 7;
    float nu = red[0][n * 16 + k];
    float de = red[0][n * 16 + 8 + k];
    size_t idx = ((size_t)n * K_B + k) * J_F + j;
    float vo = V[idx];
    V[idx] = fmaxf(vo * sqrtf(nu / de), NMF_EPS);
  }
}

// -------- weighted covariance partials, BOTH n per thread --------
template<int PK, int TILES>
__global__ __launch_bounds__(256) void k_d_partial(const float4* __restrict__ Xp,
                                                   const float2* __restrict__ X,
                                                   const float* __restrict__ T,
                                                   const float* __restrict__ V,
                                                   float* __restrict__ Dpart) {
  constexpr int TSZ = J_F / TILES;
  const int w = swz<9 * TILES>(blockIdx.x);
  const int yb = w / 9, xb = w % 9;
  __shared__ float Vl[2][K_B][TSZ];
  const int tid = threadIdx.x;
  const int j0 = yb * TSZ;
  for (int idx = tid; idx < 2 * K_B * TSZ; idx += 256) {
    int n = idx / (K_B * TSZ);
    int rr = idx % (K_B * TSZ);
    int k = rr / TSZ, jj = rr % TSZ;
    Vl[n][k][jj] = V[((size_t)n * K_B + k) * J_F + j0 + jj];
  }
  __syncthreads();
  const int i = xb * 256 + tid;
  if (i >= I_F) return;
  float tr0[K_B], tr1[K_B];
#pragma unroll
  for (int k = 0; k < K_B; ++k) {
    tr0[k] = T[(size_t)i * K_B + k];
    tr1[k] = T[((size_t)I_F + i) * K_B + k];
  }
  float a00 = 0.f, a11 = 0.f, a01r = 0.f, a01i = 0.f;
  float b00 = 0.f, b11 = 0.f, b01r = 0.f, b01i = 0.f;
#pragma unroll 2
  for (int jj = 0; jj < TSZ; ++jj) {
    float4 x = load_x(Xp, X, PK, (size_t)(j0 + jj), i);
    float R0 = 0.f, R1 = 0.f;
#pragma unroll
    for (int k = 0; k < K_B; ++k) {
      R0 += tr0[k] * Vl[0][k][jj];
      R1 += tr1[k] * Vl[1][k][jj];
    }
    float wv0 = 1.0f / (R0 + IP_EPS);
    float wv1 = 1.0f / (R1 + IP_EPS);
    float p00 = x.x * x.x + x.y * x.y;
    float p11 = x.z * x.z + x.w * x.w;
    float pr = x.x * x.z + x.y * x.w;
    float pi = x.y * x.z - x.x * x.w;
    a00 += wv0 * p00; a11 += wv0 * p11; a01r += wv0 * pr; a01i += wv0 * pi;
    b00 += wv1 * p00; b11 += wv1 * p11; b01r += wv1 * pr; b01i += wv1 * pi;
  }
  ((float4*)Dpart)[((size_t)0 * TILES + yb) * I_F + i] = make_float4(a00, a11, a01r, a01i);
  ((float4*)Dpart)[((size_t)1 * TILES + yb) * I_F + i] = make_float4(b00, b11, b01r, b01i);
}

// -------- D combine (4 lanes per i) + sequential 2x2 complex solves --------
template<int TILES>
__global__ __launch_bounds__(256) void k_d_solve(const float* __restrict__ Dpart,
                                                 float* __restrict__ W) {
  const int g = blockIdx.x * 256 + threadIdx.x;
  const int i = g >> 2;
  const int part = g & 3;
  if (i >= I_F) return;
  constexpr int per = TILES / 4;
  float4 wa = ((const float4*)W)[i * 2];
  float4 wb = ((const float4*)W)[i * 2 + 1];
  float w00r = wa.x, w00i = wa.y, w01r = wa.z, w01i = wa.w;
  float w10r = wb.x, w10i = wb.y, w11r = wb.z, w11i = wb.w;
  const float invJ = 1.0f / (float)J_F;
#pragma unroll
  for (int n = 0; n < 2; ++n) {
    const float4* dp = (const float4*)Dpart + (size_t)n * TILES * I_F + i;
    float d00 = 0.f, d11 = 0.f, d01r = 0.f, d01i = 0.f;
#pragma unroll 2
    for (int c = part * per; c < part * per + per; ++c) {
      float4 e = dp[(size_t)c * I_F];
      d00 += e.x; d11 += e.y; d01r += e.z; d01i += e.w;
    }
#pragma unroll
    for (int off = 1; off < 4; off <<= 1) {
      d00 += __shfl_xor(d00, off, 64);
      d11 += __shfl_xor(d11, off, 64);
      d01r += __shfl_xor(d01r, off, 64);
      d01i += __shfl_xor(d01i, off, 64);
    }
    d00 = d00 * invJ + IP_EPS;
    d11 = d11 * invJ + IP_EPS;
    d01r *= invJ; d01i *= invJ;
    float A00r = w00r * d00 + (w01r * d01r + w01i * d01i);
    float A00i = w00i * d00 + (w01i * d01r - w01r * d01i);
    float A01r = (w00r * d01r - w00i * d01i) + w01r * d11;
    float A01i = (w00r * d01i + w00i * d01r) + w01i * d11;
    float A10r = w10r * d00 + (w11r * d01r + w11i * d01i);
    float A10i = w10i * d00 + (w11i * d01r - w11r * d01i);
    float A11r = (w10r * d01r - w10i * d01i) + w11r * d11;
    float A11i = (w10r * d01i + w10i * d01r) + w11i * d11;
    float detr = (A00r * A11r - A00i * A11i) - (A01r * A10r - A01i * A10i);
    float deti = (A00r * A11i + A00i * A11r) - (A01r * A10i + A01i * A10r);
    float idet = 1.0f / (detr * detr + deti * deti);
    float n0r, n0i, n1r, n1i;
    if (n == 0) { n0r = A11r; n0i = A11i; n1r = -A10r; n1i = -A10i; }
    else        { n0r = -A01r; n0i = -A01i; n1r = A00r; n1i = A00i; }
    float b0r = (n0r * detr + n0i * deti) * idet;
    float b0i = (n0i * detr - n0r * deti) * idet;
    float b1r = (n1r * detr + n1i * deti) * idet;
    float b1i = (n1i * detr - n1r * deti) * idet;
    float cr = d01r * b1r - d01i * b1i;
    float ci = d01r * b1i + d01i * b1r;
    float quad = d00 * (b0r * b0r + b0i * b0i) + d11 * (b1r * b1r + b1i * b1i)
               + 2.0f * (b0r * cr + b0i * ci);
    float s = 1.0f / sqrtf(quad + IP_EPS);
    if (n == 0) { w00r = b0r * s; w00i = -b0i * s; w01r = b1r * s; w01i = -b1i * s; }
    else        { w10r = b0r * s; w10i = -b0i * s; w11r = b1r * s; w11i = -b1i * s; }
  }
  if (part == 0) {
    ((float4*)W)[i * 2]     = make_float4(w00r, w00i, w01r, w01i);
    ((float4*)W)[i * 2 + 1] = make_float4(w10r, w10i, w11r, w11i);
  }
}

// ---------------- final: out[n][j][i][2] = Y[i,n,j] ----------------
template<int PK>
__global__ __launch_bounds__(256) void k_final(const float4* __restrict__ Xp,
                                               const float2* __restrict__ X,
                                               const float* __restrict__ W,
                                               float2* __restrict__ out) {
  const int i = blockIdx.x * 256 + threadIdx.x;
  if (i >= I_F) return;
  const float4 wa = ((const float4*)W)[i * 2];
  const float4 wb = ((const float4*)W)[i * 2 + 1];
  const int j0 = blockIdx.y * 8;
  const int jend = min(8, J_F - j0);
  for (int jj = 0; jj < jend; ++jj) {
    const int j = j0 + jj;
    float4 x = load_x(Xp, X, PK, (size_t)j, i);
    float y0r = wa.x * x.x - wa.y * x.y + wa.z * x.z - wa.w * x.w;
    float y0i = wa.x * x.y + wa.y * x.x + wa.z * x.w + wa.w * x.z;
    out[(size_t)j * I_F + i] = make_float2(y0r, y0i);
    float y1r = wb.x * x.x - wb.y * x.y + wb.z * x.z - wb.w * x.w;
    float y1i = wb.x * x.y + wb.y * x.x + wb.z * x.w + wb.w * x.z;
    out[(size_t)(J_F + j) * I_F + i] = make_float2(y1r, y1i);
  }
}

extern "C" void kernel_launch(void* const* d_in, const int* in_sizes, int n_in,
                              void* d_out, int out_size, void* d_ws, size_t ws_size,
                              hipStream_t stream) {
  const float2* X = (const float2*)d_in[0];
  const float* T0 = (const float*)d_in[1];
  const float* V0 = (const float*)d_in[2];
  char* ws = (char*)d_ws;
  size_t off = 0;
  auto alloc = [&](size_t bytes) -> void* {
    void* p = ws + off;
    off = (off + bytes + 255) & ~(size_t)255;
    return p;
  };
  float* W = (float*)alloc((size_t)I_F * 8 * 4);
  float* T = (float*)alloc((size_t)2 * I_F * K_B * 4);
  float* V = (float*)alloc((size_t)2 * K_B * J_F * 4);
  const size_t scr200 = (size_t)2 * 200 * I_F * 16 * 4;  // 52.4 MB
  const size_t scr100 = (size_t)2 * 100 * I_F * 16 * 4;  // 26.2 MB
  const size_t xp_sz = (size_t)J_F * I_F * 16;           // 65.6 MB
  int cfg;
  if (off + scr200 + 256 + xp_sz <= ws_size) cfg = 0;       // packed, 200 tiles
  else if (off + scr100 + 256 + xp_sz <= ws_size) cfg = 1;  // packed, 100 tiles
  else cfg = 2;                                             // unpacked, 100 tiles
  float* Scr = (float*)alloc(cfg == 0 ? scr200 : scr100);
  float4* Xp = (cfg <= 1) ? (float4*)alloc(xp_sz) : nullptr;
  float* Tpart = Scr;
  float* Dpart = Scr;

  k_init<<<128, 256, 0, stream>>>(T0, V0, T, V, W);
  if (cfg == 0) {
    k_pack<<<dim3(9, 250), 256, 0, stream>>>(X, Xp);
    for (int it = 0; it < N_IT; ++it) {
      k_T_partial<1, 200><<<1800, 256, 0, stream>>>(Xp, X, W, T, V, Tpart);
      k_t_finish<200><<<513, 256, 0, stream>>>(Tpart, T);
      k_v_update<1><<<J_F, 256, 0, stream>>>(Xp, X, W, T, V);
      k_d_partial<1, 200><<<1800, 256, 0, stream>>>(Xp, X, T, V, Dpart);
      k_d_solve<200><<<33, 256, 0, stream>>>(Dpart, W);
    }
    k_final<1><<<dim3(9, 250), 256, 0, stream>>>(Xp, X, W, (float2*)d_out);
  } else if (cfg == 1) {
    k_pack<<<dim3(9, 250), 256, 0, stream>>>(X, Xp);
    for (int it = 0; it < N_IT; ++it) {
      k_T_partial<1, 100><<<900, 256, 0, stream>>>(Xp, X, W, T, V, Tpart);
      k_t_finish<100><<<513, 256, 0, stream>>>(Tpart, T);
      k_v_update<1><<<J_F, 256, 0, stream>>>(Xp, X, W, T, V);
      k_d_partial<1, 100><<<900, 256, 0, stream>>>(Xp, X, T, V, Dpart);
      k_d_solve<100><<<33, 256, 0, stream>>>(Dpart, W);
    }
    k_final<1><<<dim3(9, 250), 256, 0, stream>>>(Xp, X, W, (float2*)d_out);
  } else {
    for (int it = 0; it < N_IT; ++it) {
      k_T_partial<0, 100><<<900, 256, 0, stream>>>(nullptr, X, W, T, V, Tpart);
      k_t_finish<100><<<513, 256, 0, stream>>>(Tpart, T);
      k_v_update<0><<<J_F, 256, 0, stream>>>(nullptr, X, W, T, V);
      k_d_partial<0, 100><<<900, 256, 0, stream>>>(nullptr, X, T, V, Dpart);
      k_d_solve<100><<<33, 256, 0, stream>>>(Dpart, W);
    }
    k_final<0><<<dim3(9, 250), 256, 0, stream>>>(nullptr, X, W, (float2*)d_out);
  }
}

// Round 11
// 511.713 us; speedup vs baseline: 1.1261x; 1.1261x over previous
//
#include <hip/hip_runtime.h>
#include <hip/hip_bf16.h>

#define M_CH 2
#define J_F 2000
#define I_F 2049
#define K_B 8
#define N_IT 5
#define NMF_EPS 1e-20f
#define IP_EPS 1e-20f
#define TILES 100   // j-tiles for both scans
#define TSZ 20      // 100*20 = 2000
#define SJ 4        // j's per staged subtile
#define NS 5        // TSZ/SJ subtiles

// async global->LDS, 16B per lane; LDS dest is wave-uniform base + lane*16
#define GLD16(g, l)                                                            \
  __builtin_amdgcn_global_load_lds(                                            \
      (const __attribute__((address_space(1))) void*)(g),                      \
      (__attribute__((address_space(3))) void*)(l), 16, 0, 0)

// bijective XCD swizzle for NB blocks over 8 XCDs (m204 formula)
template<int NB>
__device__ __forceinline__ int swz(int orig) {
  constexpr int q = NB / 8, r = NB % 8;
  int xcd = orig & 7, rest = orig >> 3;
  return (xcd < r ? xcd * (q + 1) : r * (q + 1) + (xcd - r) * q) + rest;
}

// ---------------- init: T[n][i][k], V[n][k][j], W[i] = eye ----------------
__global__ void k_init(const float* __restrict__ T0, const float* __restrict__ V0,
                       float* __restrict__ T, float* __restrict__ V, float* __restrict__ W) {
  int t = blockIdx.x * blockDim.x + threadIdx.x;
  int stride = gridDim.x * blockDim.x;
  for (int idx = t; idx < 2 * I_F * K_B; idx += stride) {
    int n = idx / (I_F * K_B);
    int r = idx % (I_F * K_B);
    int i = r / K_B, k = r % K_B;
    T[idx] = T0[(i * K_B + k) * M_CH + n];
  }
  for (int idx = t; idx < 2 * K_B * J_F; idx += stride) {
    int n = idx / (K_B * J_F);
    int r = idx % (K_B * J_F);
    int k = r / J_F, j = r % J_F;
    V[idx] = V0[(k * J_F + j) * M_CH + n];
  }
  for (int i = t; i < I_F; i += stride) {
    W[i * 8 + 0] = 1.f; W[i * 8 + 1] = 0.f; W[i * 8 + 2] = 0.f; W[i * 8 + 3] = 0.f;
    W[i * 8 + 4] = 0.f; W[i * 8 + 5] = 0.f; W[i * 8 + 6] = 1.f; W[i * 8 + 7] = 0.f;
  }
}

// ------------- pack X: Xp[j][i] = (x0r,x0i,x1r,x1i) -------------
__global__ __launch_bounds__(256) void k_pack(const float2* __restrict__ X,
                                              float4* __restrict__ Xp) {
  const int i = blockIdx.x * 256 + threadIdx.x;
  if (i >= I_F) return;
  const int j0 = blockIdx.y * 8;
  const int jend = min(8, J_F - j0);
  for (int jj = 0; jj < jend; ++jj) {
    const int j = j0 + jj;
    float2 a = X[(size_t)j * I_F + i];
    float2 b = X[(size_t)(J_F + j) * I_F + i];
    Xp[(size_t)j * I_F + i] = make_float4(a.x, a.y, b.x, b.y);
  }
}

__device__ __forceinline__ float4 load_x(const float4* Xp, const float2* X,
                                         int pk, size_t j, int i) {
  if (pk) return Xp[j * I_F + i];
  float2 a = X[j * I_F + i];
  float2 b = X[(size_t)J_F * I_F + j * I_F + i];
  return make_float4(a.x, a.y, b.x, b.y);
}

// ==== T-update partials, both n, LDS-staged Xp (double-buffered gload_lds) ====
__global__ __launch_bounds__(256) void k_T_stage(const float4* __restrict__ Xp,
                                                 const float* __restrict__ W,
                                                 const float* __restrict__ T,
                                                 const float* __restrict__ V,
                                                 float* __restrict__ Tpart) {
  const int w = swz<9 * TILES>(blockIdx.x);
  const int yb = w / 9, xb = w % 9;
  __shared__ float4 Xl[2][SJ][256];
  __shared__ float Vl[2][K_B][TSZ];
  const int tid = threadIdx.x;
  const int wv = tid >> 6;
  const int lane = tid & 63;
  const int j0 = yb * TSZ;
  const int i0 = xb * 256;
  for (int idx = tid; idx < 2 * K_B * TSZ; idx += 256) {
    int n = idx / (K_B * TSZ);
    int rr = idx % (K_B * TSZ);
    int k = rr / TSZ, jj = rr % TSZ;
    Vl[n][k][jj] = V[((size_t)n * K_B + k) * J_F + j0 + jj];
  }
  // issue batch 0 (each wave loads its own 64-i chunk for SJ j's)
#pragma unroll
  for (int jj = 0; jj < SJ; ++jj)
    GLD16(Xp + (size_t)(j0 + jj) * I_F + i0 + wv * 64 + lane, &Xl[0][jj][wv * 64]);
  const int i = i0 + tid;
  const int ic = min(i, I_F - 1);
  float tr0[K_B], tr1[K_B];
#pragma unroll
  for (int k = 0; k < K_B; ++k) {
    tr0[k] = T[(size_t)ic * 8 + k];
    tr1[k] = T[((size_t)I_F + ic) * 8 + k];
  }
  const float4 w0 = ((const float4*)W)[ic * 2];
  const float4 w1 = ((const float4*)W)[ic * 2 + 1];
  float num0[K_B] = {}, den0[K_B] = {}, num1[K_B] = {}, den1[K_B] = {};
  for (int s = 0; s < NS; ++s) {
    __syncthreads();              // drains batch s (vmcnt(0) before s_barrier)
    if (s + 1 < NS) {
#pragma unroll
      for (int jj = 0; jj < SJ; ++jj)
        GLD16(Xp + (size_t)(j0 + (s + 1) * SJ + jj) * I_F + i0 + wv * 64 + lane,
              &Xl[(s + 1) & 1][jj][wv * 64]);
    }
    const int buf = s & 1;
#pragma unroll
    for (int jj = 0; jj < SJ; ++jj) {
      float4 x = Xl[buf][jj][tid];
      const int jl = s * SJ + jj;
      float yr = w0.x * x.x - w0.y * x.y + w0.z * x.z - w0.w * x.w;
      float yi = w0.x * x.y + w0.y * x.x + w0.z * x.w + w0.w * x.z;
      float p0 = yr * yr + yi * yi;
      float zr = w1.x * x.x - w1.y * x.y + w1.z * x.z - w1.w * x.w;
      float zi = w1.x * x.y + w1.y * x.x + w1.z * x.w + w1.w * x.z;
      float p1 = zr * zr + zi * zi;
      float R0 = 0.f, R1 = 0.f;
#pragma unroll
      for (int k = 0; k < K_B; ++k) {
        R0 += tr0[k] * Vl[0][k][jl];
        R1 += tr1[k] * Vl[1][k][jl];
      }
      float a0 = p0 / (R0 * R0), b0 = 1.0f / R0;
      float a1 = p1 / (R1 * R1), b1 = 1.0f / R1;
#pragma unroll
      for (int k = 0; k < K_B; ++k) {
        num0[k] += a0 * Vl[0][k][jl]; den0[k] += b0 * Vl[0][k][jl];
        num1[k] += a1 * Vl[1][k][jl]; den1[k] += b1 * Vl[1][k][jl];
      }
    }
  }
  if (i < I_F) {
    float* b0_ = Tpart + (((size_t)0 * TILES + yb) * I_F + i) * 16;
    float* b1_ = Tpart + (((size_t)1 * TILES + yb) * I_F + i) * 16;
    *(float4*)(b0_ + 0)  = make_float4(num0[0], num0[1], num0[2], num0[3]);
    *(float4*)(b0_ + 4)  = make_float4(num0[4], num0[5], num0[6], num0[7]);
    *(float4*)(b0_ + 8)  = make_float4(den0[0], den0[1], den0[2], den0[3]);
    *(float4*)(b0_ + 12) = make_float4(den0[4], den0[5], den0[6], den0[7]);
    *(float4*)(b1_ + 0)  = make_float4(num1[0], num1[1], num1[2], num1[3]);
    *(float4*)(b1_ + 4)  = make_float4(num1[4], num1[5], num1[6], num1[7]);
    *(float4*)(b1_ + 8)  = make_float4(den1[0], den1[1], den1[2], den1[3]);
    *(float4*)(b1_ + 12) = make_float4(den1[4], den1[5], den1[6], den1[7]);
  }
}

// ==== D partials, both n, LDS-staged Xp (double-buffered gload_lds) ====
__global__ __launch_bounds__(256) void k_d_stage(const float4* __restrict__ Xp,
                                                 const float* __restrict__ T,
                                                 const float* __restrict__ V,
                                                 float* __restrict__ Dpart) {
  const int w = swz<9 * TILES>(blockIdx.x);
  const int yb = w / 9, xb = w % 9;
  __shared__ float4 Xl[2][SJ][256];
  __shared__ float Vl[2][K_B][TSZ];
  const int tid = threadIdx.x;
  const int wv = tid >> 6;
  const int lane = tid & 63;
  const int j0 = yb * TSZ;
  const int i0 = xb * 256;
  for (int idx = tid; idx < 2 * K_B * TSZ; idx += 256) {
    int n = idx / (K_B * TSZ);
    int rr = idx % (K_B * TSZ);
    int k = rr / TSZ, jj = rr % TSZ;
    Vl[n][k][jj] = V[((size_t)n * K_B + k) * J_F + j0 + jj];
  }
#pragma unroll
  for (int jj = 0; jj < SJ; ++jj)
    GLD16(Xp + (size_t)(j0 + jj) * I_F + i0 + wv * 64 + lane, &Xl[0][jj][wv * 64]);
  const int i = i0 + tid;
  const int ic = min(i, I_F - 1);
  float tr0[K_B], tr1[K_B];
#pragma unroll
  for (int k = 0; k < K_B; ++k) {
    tr0[k] = T[(size_t)ic * K_B + k];
    tr1[k] = T[((size_t)I_F + ic) * K_B + k];
  }
  float a00 = 0.f, a11 = 0.f, a01r = 0.f, a01i = 0.f;
  float b00 = 0.f, b11 = 0.f, b01r = 0.f, b01i = 0.f;
  for (int s = 0; s < NS; ++s) {
    __syncthreads();
    if (s + 1 < NS) {
#pragma unroll
      for (int jj = 0; jj < SJ; ++jj)
        GLD16(Xp + (size_t)(j0 + (s + 1) * SJ + jj) * I_F + i0 + wv * 64 + lane,
              &Xl[(s + 1) & 1][jj][wv * 64]);
    }
    const int buf = s & 1;
#pragma unroll
    for (int jj = 0; jj < SJ; ++jj) {
      float4 x = Xl[buf][jj][tid];
      const int jl = s * SJ + jj;
      float R0 = 0.f, R1 = 0.f;
#pragma unroll
      for (int k = 0; k < K_B; ++k) {
        R0 += tr0[k] * Vl[0][k][jl];
        R1 += tr1[k] * Vl[1][k][jl];
      }
      float wv0 = 1.0f / (R0 + IP_EPS);
      float wv1 = 1.0f / (R1 + IP_EPS);
      float p00 = x.x * x.x + x.y * x.y;
      float p11 = x.z * x.z + x.w * x.w;
      float pr = x.x * x.z + x.y * x.w;
      float pi = x.y * x.z - x.x * x.w;
      a00 += wv0 * p00; a11 += wv0 * p11; a01r += wv0 * pr; a01i += wv0 * pi;
      b00 += wv1 * p00; b11 += wv1 * p11; b01r += wv1 * pr; b01i += wv1 * pi;
    }
  }
  if (i < I_F) {
    ((float4*)Dpart)[((size_t)0 * TILES + yb) * I_F + i] = make_float4(a00, a11, a01r, a01i);
    ((float4*)Dpart)[((size_t)1 * TILES + yb) * I_F + i] = make_float4(b00, b11, b01r, b01i);
  }
}

// ---- plain (unpacked) fallback scans, R9 structure ----
__global__ __launch_bounds__(256) void k_T_plain(const float2* __restrict__ X,
                                                 const float* __restrict__ W,
                                                 const float* __restrict__ T,
                                                 const float* __restrict__ V,
                                                 float* __restrict__ Tpart) {
  const int w = swz<9 * TILES>(blockIdx.x);
  const int yb = w / 9, xb = w % 9;
  __shared__ float Vl[2][K_B][TSZ];
  const int tid = threadIdx.x;
  const int j0 = yb * TSZ;
  for (int idx = tid; idx < 2 * K_B * TSZ; idx += 256) {
    int n = idx / (K_B * TSZ);
    int rr = idx % (K_B * TSZ);
    int k = rr / TSZ, jj = rr % TSZ;
    Vl[n][k][jj] = V[((size_t)n * K_B + k) * J_F + j0 + jj];
  }
  __syncthreads();
  const int i = xb * 256 + tid;
  if (i >= I_F) return;
  float tr0[K_B], tr1[K_B];
#pragma unroll
  for (int k = 0; k < K_B; ++k) {
    tr0[k] = T[(size_t)i * 8 + k];
    tr1[k] = T[((size_t)I_F + i) * 8 + k];
  }
  const float4 w0 = ((const float4*)W)[i * 2];
  const float4 w1 = ((const float4*)W)[i * 2 + 1];
  float num0[K_B] = {}, den0[K_B] = {}, num1[K_B] = {}, den1[K_B] = {};
#pragma unroll 2
  for (int jj = 0; jj < TSZ; ++jj) {
    float4 x = load_x(nullptr, X, 0, (size_t)(j0 + jj), i);
    float yr = w0.x * x.x - w0.y * x.y + w0.z * x.z - w0.w * x.w;
    float yi = w0.x * x.y + w0.y * x.x + w0.z * x.w + w0.w * x.z;
    float p0 = yr * yr + yi * yi;
    float zr = w1.x * x.x - w1.y * x.y + w1.z * x.z - w1.w * x.w;
    float zi = w1.x * x.y + w1.y * x.x + w1.z * x.w + w1.w * x.z;
    float p1 = zr * zr + zi * zi;
    float R0 = 0.f, R1 = 0.f;
#pragma unroll
    for (int k = 0; k < K_B; ++k) {
      R0 += tr0[k] * Vl[0][k][jj];
      R1 += tr1[k] * Vl[1][k][jj];
    }
    float a0 = p0 / (R0 * R0), b0 = 1.0f / R0;
    float a1 = p1 / (R1 * R1), b1 = 1.0f / R1;
#pragma unroll
    for (int k = 0; k < K_B; ++k) {
      num0[k] += a0 * Vl[0][k][jj]; den0[k] += b0 * Vl[0][k][jj];
      num1[k] += a1 * Vl[1][k][jj]; den1[k] += b1 * Vl[1][k][jj];
    }
  }
  float* b0_ = Tpart + (((size_t)0 * TILES + yb) * I_F + i) * 16;
  float* b1_ = Tpart + (((size_t)1 * TILES + yb) * I_F + i) * 16;
  *(float4*)(b0_ + 0)  = make_float4(num0[0], num0[1], num0[2], num0[3]);
  *(float4*)(b0_ + 4)  = make_float4(num0[4], num0[5], num0[6], num0[7]);
  *(float4*)(b0_ + 8)  = make_float4(den0[0], den0[1], den0[2], den0[3]);
  *(float4*)(b0_ + 12) = make_float4(den0[4], den0[5], den0[6], den0[7]);
  *(float4*)(b1_ + 0)  = make_float4(num1[0], num1[1], num1[2], num1[3]);
  *(float4*)(b1_ + 4)  = make_float4(num1[4], num1[5], num1[6], num1[7]);
  *(float4*)(b1_ + 8)  = make_float4(den1[0], den1[1], den1[2], den1[3]);
  *(float4*)(b1_ + 12) = make_float4(den1[4], den1[5], den1[6], den1[7]);
}

__global__ __launch_bounds__(256) void k_d_plain(const float2* __restrict__ X,
                                                 const float* __restrict__ T,
                                                 const float* __restrict__ V,
                                                 float* __restrict__ Dpart) {
  const int w = swz<9 * TILES>(blockIdx.x);
  const int yb = w / 9, xb = w % 9;
  __shared__ float Vl[2][K_B][TSZ];
  const int tid = threadIdx.x;
  const int j0 = yb * TSZ;
  for (int idx = tid; idx < 2 * K_B * TSZ; idx += 256) {
    int n = idx / (K_B * TSZ);
    int rr = idx % (K_B * TSZ);
    int k = rr / TSZ, jj = rr % TSZ;
    Vl[n][k][jj] = V[((size_t)n * K_B + k) * J_F + j0 + jj];
  }
  __syncthreads();
  const int i = xb * 256 + tid;
  if (i >= I_F) return;
  float tr0[K_B], tr1[K_B];
#pragma unroll
  for (int k = 0; k < K_B; ++k) {
    tr0[k] = T[(size_t)i * K_B + k];
    tr1[k] = T[((size_t)I_F + i) * K_B + k];
  }
  float a00 = 0.f, a11 = 0.f, a01r = 0.f, a01i = 0.f;
  float b00 = 0.f, b11 = 0.f, b01r = 0.f, b01i = 0.f;
#pragma unroll 2
  for (int jj = 0; jj < TSZ; ++jj) {
    float4 x = load_x(nullptr, X, 0, (size_t)(j0 + jj), i);
    float R0 = 0.f, R1 = 0.f;
#pragma unroll
    for (int k = 0; k < K_B; ++k) {
      R0 += tr0[k] * Vl[0][k][jj];
      R1 += tr1[k] * Vl[1][k][jj];
    }
    float wv0 = 1.0f / (R0 + IP_EPS);
    float wv1 = 1.0f / (R1 + IP_EPS);
    float p00 = x.x * x.x + x.y * x.y;
    float p11 = x.z * x.z + x.w * x.w;
    float pr = x.x * x.z + x.y * x.w;
    float pi = x.y * x.z - x.x * x.w;
    a00 += wv0 * p00; a11 += wv0 * p11; a01r += wv0 * pr; a01i += wv0 * pi;
    b00 += wv1 * p00; b11 += wv1 * p11; b01r += wv1 * pr; b01i += wv1 * pi;
  }
  ((float4*)Dpart)[((size_t)0 * TILES + yb) * I_F + i] = make_float4(a00, a11, a01r, a01i);
  ((float4*)Dpart)[((size_t)1 * TILES + yb) * I_F + i] = make_float4(b00, b11, b01r, b01i);
}

// ---------------- finish T update from partials (ILP-4) ----------------
__global__ __launch_bounds__(256) void k_t_finish(const float* __restrict__ Tpart,
                                                  float* __restrict__ T) {
  int t = blockIdx.x * 256 + threadIdx.x;
  if (t >= 2 * I_F * K_B) return;
  int n = t / (I_F * K_B);
  int r = t % (I_F * K_B);
  int i = r >> 3, k = r & 7;
  const float* p = Tpart + (((size_t)n * TILES) * I_F + i) * 16;
  const size_t S = (size_t)I_F * 16;
  float n0 = 0.f, n1 = 0.f, n2 = 0.f, n3 = 0.f;
  float d0 = 0.f, d1 = 0.f, d2 = 0.f, d3 = 0.f;
  for (int jt = 0; jt < TILES; jt += 4) {
    n0 += p[jt * S + k];       d0 += p[jt * S + 8 + k];
    n1 += p[(jt + 1) * S + k]; d1 += p[(jt + 1) * S + 8 + k];
    n2 += p[(jt + 2) * S + k]; d2 += p[(jt + 2) * S + 8 + k];
    n3 += p[(jt + 3) * S + k]; d3 += p[(jt + 3) * S + 8 + k];
  }
  float num = (n0 + n1) + (n2 + n3);
  float den = (d0 + d1) + (d2 + d3);
  float told = T[t];
  T[t] = fmaxf(told * sqrtf(num / den), NMF_EPS);
}

// -- V update: block per j, both n, recompute P from Xp, full i-reduce, in place --
template<int PK>
__global__ __launch_bounds__(256) void k_v_update(const float4* __restrict__ Xp,
                                                  const float2* __restrict__ X,
                                                  const float* __restrict__ W,
                                                  const float* __restrict__ T,
                                                  float* __restrict__ V) {
  const int j = blockIdx.x;
  const int tid = threadIdx.x;
  float vold0[K_B], vold1[K_B];
#pragma unroll
  for (int k = 0; k < K_B; ++k) {
    vold0[k] = V[(size_t)k * J_F + j];
    vold1[k] = V[(size_t)(K_B + k) * J_F + j];
  }
  float num0[K_B] = {}, den0[K_B] = {}, num1[K_B] = {}, den1[K_B] = {};
  const float* T1 = T + (size_t)I_F * K_B;
  for (int i = tid; i < I_F; i += 256) {
    float4 x = load_x(Xp, X, PK, (size_t)j, i);
    const float4 wa = ((const float4*)W)[i * 2];
    const float4 wb = ((const float4*)W)[i * 2 + 1];
    float yr = wa.x * x.x - wa.y * x.y + wa.z * x.z - wa.w * x.w;
    float yi = wa.x * x.y + wa.y * x.x + wa.z * x.w + wa.w * x.z;
    float p0 = yr * yr + yi * yi;
    float zr = wb.x * x.x - wb.y * x.y + wb.z * x.z - wb.w * x.w;
    float zi = wb.x * x.y + wb.y * x.x + wb.z * x.w + wb.w * x.z;
    float p1 = zr * zr + zi * zi;
    const float4 ta = *(const float4*)&T[i * 8];
    const float4 tb = *(const float4*)&T[i * 8 + 4];
    const float4 tc = *(const float4*)&T1[i * 8];
    const float4 td = *(const float4*)&T1[i * 8 + 4];
    float t0[K_B] = {ta.x, ta.y, ta.z, ta.w, tb.x, tb.y, tb.z, tb.w};
    float t1[K_B] = {tc.x, tc.y, tc.z, tc.w, td.x, td.y, td.z, td.w};
    float R0 = 0.f, R1 = 0.f;
#pragma unroll
    for (int k = 0; k < K_B; ++k) { R0 += t0[k] * vold0[k]; R1 += t1[k] * vold1[k]; }
    float a0 = p0 / (R0 * R0), b0 = 1.0f / R0;
    float a1 = p1 / (R1 * R1), b1 = 1.0f / R1;
#pragma unroll
    for (int k = 0; k < K_B; ++k) {
      num0[k] += a0 * t0[k]; den0[k] += b0 * t0[k];
      num1[k] += a1 * t1[k]; den1[k] += b1 * t1[k];
    }
  }
  __shared__ float red[4][32];
  const int lane = tid & 63, wid = tid >> 6;
#pragma unroll
  for (int k = 0; k < K_B; ++k) {
    float a0 = num0[k], b0 = den0[k], a1 = num1[k], b1 = den1[k];
#pragma unroll
    for (int off = 32; off > 0; off >>= 1) {
      a0 += __shfl_xor(a0, off, 64);
      b0 += __shfl_xor(b0, off, 64);
      a1 += __shfl_xor(a1, off, 64);
      b1 += __shfl_xor(b1, off, 64);
    }
    if (lane == 0) {
      red[wid][k] = a0; red[wid][8 + k] = b0;
      red[wid][16 + k] = a1; red[wid][24 + k] = b1;
    }
  }
  __syncthreads();
  if (tid < 32) red[0][tid] = red[0][tid] + red[1][tid] + red[2][tid] + red[3][tid];
  __syncthreads();
  if (tid < 16) {
    int n = tid >> 3, k = tid & 7;
    float nu = red[0][n * 16 + k];
    float de = red[0][n * 16 + 8 + k];
    size_t idx = ((size_t)n * K_B + k) * J_F + j;
    float vo = V[idx];
    V[idx] = fmaxf(vo * sqrtf(nu / de), NMF_EPS);
  }
}

// -------- D combine (4 lanes per i) + sequential 2x2 complex solves --------
__global__ __launch_bounds__(256) void k_d_solve(const float* __restrict__ Dpart,
                                                 float* __restrict__ W) {
  const int g = blockIdx.x * 256 + threadIdx.x;
  const int i = g >> 2;
  const int part = g & 3;
  if (i >= I_F) return;
  float4 wa = ((const float4*)W)[i * 2];
  float4 wb = ((const float4*)W)[i * 2 + 1];
  float w00r = wa.x, w00i = wa.y, w01r = wa.z, w01i = wa.w;
  float w10r = wb.x, w10i = wb.y, w11r = wb.z, w11i = wb.w;
  const float invJ = 1.0f / (float)J_F;
#pragma unroll
  for (int n = 0; n < 2; ++n) {
    const float4* dp = (const float4*)Dpart + (size_t)n * TILES * I_F + i;
    float d00 = 0.f, d11 = 0.f, d01r = 0.f, d01i = 0.f;
    for (int c = part * 25; c < part * 25 + 25; ++c) {
      float4 e = dp[(size_t)c * I_F];
      d00 += e.x; d11 += e.y; d01r += e.z; d01i += e.w;
    }
#pragma unroll
    for (int off = 1; off < 4; off <<= 1) {
      d00 += __shfl_xor(d00, off, 64);
      d11 += __shfl_xor(d11, off, 64);
      d01r += __shfl_xor(d01r, off, 64);
      d01i += __shfl_xor(d01i, off, 64);
    }
    d00 = d00 * invJ + IP_EPS;
    d11 = d11 * invJ + IP_EPS;
    d01r *= invJ; d01i *= invJ;
    float A00r = w00r * d00 + (w01r * d01r + w01i * d01i);
    float A00i = w00i * d00 + (w01i * d01r - w01r * d01i);
    float A01r = (w00r * d01r - w00i * d01i) + w01r * d11;
    float A01i = (w00r * d01i + w00i * d01r) + w01i * d11;
    float A10r = w10r * d00 + (w11r * d01r + w11i * d01i);
    float A10i = w10i * d00 + (w11i * d01r - w11r * d01i);
    float A11r = (w10r * d01r - w10i * d01i) + w11r * d11;
    float A11i = (w10r * d01i + w10i * d01r) + w11i * d11;
    float detr = (A00r * A11r - A00i * A11i) - (A01r * A10r - A01i * A10i);
    float deti = (A00r * A11i + A00i * A11r) - (A01r * A10i + A01i * A10r);
    float idet = 1.0f / (detr * detr + deti * deti);
    float n0r, n0i, n1r, n1i;
    if (n == 0) { n0r = A11r; n0i = A11i; n1r = -A10r; n1i = -A10i; }
    else        { n0r = -A01r; n0i = -A01i; n1r = A00r; n1i = A00i; }
    float b0r = (n0r * detr + n0i * deti) * idet;
    float b0i = (n0i * detr - n0r * deti) * idet;
    float b1r = (n1r * detr + n1i * deti) * idet;
    float b1i = (n1i * detr - n1r * deti) * idet;
    float cr = d01r * b1r - d01i * b1i;
    float ci = d01r * b1i + d01i * b1r;
    float quad = d00 * (b0r * b0r + b0i * b0i) + d11 * (b1r * b1r + b1i * b1i)
               + 2.0f * (b0r * cr + b0i * ci);
    float s = 1.0f / sqrtf(quad + IP_EPS);
    if (n == 0) { w00r = b0r * s; w00i = -b0i * s; w01r = b1r * s; w01i = -b1i * s; }
    else        { w10r = b0r * s; w10i = -b0i * s; w11r = b1r * s; w11i = -b1i * s; }
  }
  if (part == 0) {
    ((float4*)W)[i * 2]     = make_float4(w00r, w00i, w01r, w01i);
    ((float4*)W)[i * 2 + 1] = make_float4(w10r, w10i, w11r, w11i);
  }
}

// ---------------- final: out[n][j][i][2] = Y[i,n,j] ----------------
template<int PK>
__global__ __launch_bounds__(256) void k_final(const float4* __restrict__ Xp,
                                               const float2* __restrict__ X,
                                               const float* __restrict__ W,
                                               float2* __restrict__ out) {
  const int i = blockIdx.x * 256 + threadIdx.x;
  if (i >= I_F) return;
  const float4 wa = ((const float4*)W)[i * 2];
  const float4 wb = ((const float4*)W)[i * 2 + 1];
  const int j0 = blockIdx.y * 8;
  const int jend = min(8, J_F - j0);
  for (int jj = 0; jj < jend; ++jj) {
    const int j = j0 + jj;
    float4 x = load_x(Xp, X, PK, (size_t)j, i);
    float y0r = wa.x * x.x - wa.y * x.y + wa.z * x.z - wa.w * x.w;
    float y0i = wa.x * x.y + wa.y * x.x + wa.z * x.w + wa.w * x.z;
    out[(size_t)j * I_F + i] = make_float2(y0r, y0i);
    float y1r = wb.x * x.x - wb.y * x.y + wb.z * x.z - wb.w * x.w;
    float y1i = wb.x * x.y + wb.y * x.x + wb.z * x.w + wb.w * x.z;
    out[(size_t)(J_F + j) * I_F + i] = make_float2(y1r, y1i);
  }
}

extern "C" void kernel_launch(void* const* d_in, const int* in_sizes, int n_in,
                              void* d_out, int out_size, void* d_ws, size_t ws_size,
                              hipStream_t stream) {
  const float2* X = (const float2*)d_in[0];
  const float* T0 = (const float*)d_in[1];
  const float* V0 = (const float*)d_in[2];
  char* ws = (char*)d_ws;
  size_t off = 0;
  auto alloc = [&](size_t bytes) -> void* {
    void* p = ws + off;
    off = (off + bytes + 255) & ~(size_t)255;
    return p;
  };
  float* W = (float*)alloc((size_t)I_F * 8 * 4);
  float* T = (float*)alloc((size_t)2 * I_F * K_B * 4);
  float* V = (float*)alloc((size_t)2 * K_B * J_F * 4);
  // Tpart (26.2 MB) and Dpart (13.1 MB) share (disjoint lifetimes)
  float* Scr = (float*)alloc((size_t)2 * TILES * I_F * 16 * 4);
  float* Tpart = Scr;
  float* Dpart = Scr;
  size_t off_no_pack = off;
  // +4 KB slack: staged loads of the xb=8 block run lanes past i=I_F-1
  float4* Xp = (float4*)alloc((size_t)J_F * I_F * 16 + 4096);
  const bool packed = (off <= ws_size);
  if (!packed) off = off_no_pack;

  k_init<<<128, 256, 0, stream>>>(T0, V0, T, V, W);
  if (packed) {
    k_pack<<<dim3(9, 250), 256, 0, stream>>>(X, Xp);
    for (int it = 0; it < N_IT; ++it) {
      k_T_stage<<<9 * TILES, 256, 0, stream>>>(Xp, W, T, V, Tpart);
      k_t_finish<<<129, 256, 0, stream>>>(Tpart, T);
      k_v_update<1><<<J_F, 256, 0, stream>>>(Xp, X, W, T, V);
      k_d_stage<<<9 * TILES, 256, 0, stream>>>(Xp, T, V, Dpart);
      k_d_solve<<<33, 256, 0, stream>>>(Dpart, W);
    }
    k_final<1><<<dim3(9, 250), 256, 0, stream>>>(Xp, X, W, (float2*)d_out);
  } else {
    for (int it = 0; it < N_IT; ++it) {
      k_T_plain<<<9 * TILES, 256, 0, stream>>>(X, W, T, V, Tpart);
      k_t_finish<<<129, 256, 0, stream>>>(Tpart, T);
      k_v_update<0><<<J_F, 256, 0, stream>>>(nullptr, X, W, T, V);
      k_d_plain<<<9 * TILES, 256, 0, stream>>>(X, T, V, Dpart);
      k_d_solve<<<33, 256, 0, stream>>>(Dpart, W);
    }
    k_final<0><<<dim3(9, 250), 256, 0, stream>>>(nullptr, X, W, (float2*)d_out);
  }
}

// Round 12
// 490.165 us; speedup vs baseline: 1.1756x; 1.0440x over previous
//
#include <hip/hip_runtime.h>
#include <hip/hip_bf16.h>

#define M_CH 2
#define J_F 2000
#define I_F 2049
#define K_B 8
#define N_IT 5
#define NMF_EPS 1e-20f
#define IP_EPS 1e-20f

// ---------------- init: T[n][i][k], V[n][k][j], W[i] = eye ----------------
__global__ void k_init(const float* __restrict__ T0, const float* __restrict__ V0,
                       float* __restrict__ T, float* __restrict__ V, float* __restrict__ W) {
  int t = blockIdx.x * blockDim.x + threadIdx.x;
  int stride = gridDim.x * blockDim.x;
  for (int idx = t; idx < 2 * I_F * K_B; idx += stride) {
    int n = idx / (I_F * K_B);
    int r = idx % (I_F * K_B);
    int i = r / K_B, k = r % K_B;
    T[idx] = T0[(i * K_B + k) * M_CH + n];
  }
  for (int idx = t; idx < 2 * K_B * J_F; idx += stride) {
    int n = idx / (K_B * J_F);
    int r = idx % (K_B * J_F);
    int k = r / J_F, j = r % J_F;
    V[idx] = V0[(k * J_F + j) * M_CH + n];
  }
  for (int i = t; i < I_F; i += stride) {
    W[i * 8 + 0] = 1.f; W[i * 8 + 1] = 0.f; W[i * 8 + 2] = 0.f; W[i * 8 + 3] = 0.f;
    W[i * 8 + 4] = 0.f; W[i * 8 + 5] = 0.f; W[i * 8 + 6] = 1.f; W[i * 8 + 7] = 0.f;
  }
}

// ------------- pack X j-major: Xp[j][i] = (x0r,x0i,x1r,x1i) -------------
__global__ __launch_bounds__(256) void k_pack(const float2* __restrict__ X,
                                              float4* __restrict__ Xp) {
  const int i = blockIdx.x * 256 + threadIdx.x;
  if (i >= I_F) return;
  const int j0 = blockIdx.y * 8;
  const int jend = min(8, J_F - j0);
  for (int jj = 0; jj < jend; ++jj) {
    const int j = j0 + jj;
    float2 a = X[(size_t)j * I_F + i];
    float2 b = X[(size_t)(J_F + j) * I_F + i];
    Xp[(size_t)j * I_F + i] = make_float4(a.x, a.y, b.x, b.y);
  }
}

// ------ pack X i-major via 32x32 LDS tile transpose: Xpt[i][j] ------
__global__ __launch_bounds__(256) void k_packT(const float2* __restrict__ X,
                                               float4* __restrict__ Xpt) {
  __shared__ float4 Tl[32][33];
  const int tid = threadIdx.x;
  const int i0 = blockIdx.x * 32, j0 = blockIdx.y * 32;
  const int la = tid & 31, su = tid >> 5;
#pragma unroll
  for (int p = 0; p < 4; ++p) {
    int jj = su + p * 8;
    int i = i0 + la, j = j0 + jj;
    if (i < I_F && j < J_F) {
      float2 a = X[(size_t)j * I_F + i];
      float2 b = X[(size_t)(J_F + j) * I_F + i];
      Tl[la][jj] = make_float4(a.x, a.y, b.x, b.y);
    }
  }
  __syncthreads();
#pragma unroll
  for (int p = 0; p < 4; ++p) {
    int ii = su + p * 8;
    int i = i0 + ii, j = j0 + la;
    if (i < I_F && j < J_F) Xpt[(size_t)i * J_F + j] = Tl[ii][la];
  }
}

__device__ __forceinline__ float4 load_x(const float4* Xp, const float2* X,
                                         int pk, size_t j, int i) {
  if (pk) return Xp[j * I_F + i];
  float2 a = X[j * I_F + i];
  float2 b = X[(size_t)J_F * I_F + j * I_F + i];
  return make_float4(a.x, a.y, b.x, b.y);
}

__device__ __forceinline__ float4 load_xt(const float4* Xpt, const float2* X,
                                          int pk, int i, int j) {
  if (pk) return Xpt[(size_t)i * J_F + j];
  float2 a = X[(size_t)j * I_F + i];
  float2 b = X[(size_t)(J_F + j) * I_F + i];
  return make_float4(a.x, a.y, b.x, b.y);
}

// ==== T update: one block per i, threads stride j, full reduce, in place ====
template<int PK>
__global__ __launch_bounds__(256) void k_T_rows(const float4* __restrict__ Xpt,
                                                const float2* __restrict__ X,
                                                const float* __restrict__ W,
                                                float* __restrict__ T,
                                                const float* __restrict__ V) {
  const int i = blockIdx.x;
  const int tid = threadIdx.x;
  float tr0[K_B], tr1[K_B];
#pragma unroll
  for (int k = 0; k < K_B; ++k) {
    tr0[k] = T[(size_t)i * 8 + k];
    tr1[k] = T[((size_t)I_F + i) * 8 + k];
  }
  const float4 w0 = ((const float4*)W)[i * 2];
  const float4 w1 = ((const float4*)W)[i * 2 + 1];
  float num0[K_B] = {}, den0[K_B] = {}, num1[K_B] = {}, den1[K_B] = {};
  for (int j = tid; j < J_F; j += 256) {
    float4 x = load_xt(Xpt, X, PK, i, j);
    float yr = w0.x * x.x - w0.y * x.y + w0.z * x.z - w0.w * x.w;
    float yi = w0.x * x.y + w0.y * x.x + w0.z * x.w + w0.w * x.z;
    float p0 = yr * yr + yi * yi;
    float zr = w1.x * x.x - w1.y * x.y + w1.z * x.z - w1.w * x.w;
    float zi = w1.x * x.y + w1.y * x.x + w1.z * x.w + w1.w * x.z;
    float p1 = zr * zr + zi * zi;
    float v0[K_B], v1[K_B];
    float R0 = 0.f, R1 = 0.f;
#pragma unroll
    for (int k = 0; k < K_B; ++k) {
      v0[k] = V[(size_t)k * J_F + j];           R0 += tr0[k] * v0[k];
      v1[k] = V[(size_t)(K_B + k) * J_F + j];   R1 += tr1[k] * v1[k];
    }
    float a0 = p0 / (R0 * R0), b0 = 1.0f / R0;
    float a1 = p1 / (R1 * R1), b1 = 1.0f / R1;
#pragma unroll
    for (int k = 0; k < K_B; ++k) {
      num0[k] += a0 * v0[k]; den0[k] += b0 * v0[k];
      num1[k] += a1 * v1[k]; den1[k] += b1 * v1[k];
    }
  }
  __shared__ float red[4][32];
  const int lane = tid & 63, wid = tid >> 6;
#pragma unroll
  for (int k = 0; k < K_B; ++k) {
    float a0 = num0[k], b0 = den0[k], a1 = num1[k], b1 = den1[k];
#pragma unroll
    for (int off = 32; off > 0; off >>= 1) {
      a0 += __shfl_xor(a0, off, 64);
      b0 += __shfl_xor(b0, off, 64);
      a1 += __shfl_xor(a1, off, 64);
      b1 += __shfl_xor(b1, off, 64);
    }
    if (lane == 0) {
      red[wid][k] = a0; red[wid][8 + k] = b0;
      red[wid][16 + k] = a1; red[wid][24 + k] = b1;
    }
  }
  __syncthreads();
  if (tid < 32) red[0][tid] = red[0][tid] + red[1][tid] + red[2][tid] + red[3][tid];
  __syncthreads();
  if (tid < 16) {
    int n = tid >> 3, k = tid & 7;
    float nu = red[0][n * 16 + k];
    float de = red[0][n * 16 + 8 + k];
    size_t idx = ((size_t)n * I_F + i) * 8 + k;
    float told = T[idx];
    T[idx] = fmaxf(told * sqrtf(nu / de), NMF_EPS);
  }
}

// -- V update: block per j, both n, P inline, full i-reduce, in place --
template<int PK>
__global__ __launch_bounds__(256) void k_v_update(const float4* __restrict__ Xp,
                                                  const float2* __restrict__ X,
                                                  const float* __restrict__ W,
                                                  const float* __restrict__ T,
                                                  float* __restrict__ V) {
  const int j = blockIdx.x;
  const int tid = threadIdx.x;
  float vold0[K_B], vold1[K_B];
#pragma unroll
  for (int k = 0; k < K_B; ++k) {
    vold0[k] = V[(size_t)k * J_F + j];
    vold1[k] = V[(size_t)(K_B + k) * J_F + j];
  }
  float num0[K_B] = {}, den0[K_B] = {}, num1[K_B] = {}, den1[K_B] = {};
  const float* T1 = T + (size_t)I_F * K_B;
  for (int i = tid; i < I_F; i += 256) {
    float4 x = load_x(Xp, X, PK, (size_t)j, i);
    const float4 wa = ((const float4*)W)[i * 2];
    const float4 wb = ((const float4*)W)[i * 2 + 1];
    float yr = wa.x * x.x - wa.y * x.y + wa.z * x.z - wa.w * x.w;
    float yi = wa.x * x.y + wa.y * x.x + wa.z * x.w + wa.w * x.z;
    float p0 = yr * yr + yi * yi;
    float zr = wb.x * x.x - wb.y * x.y + wb.z * x.z - wb.w * x.w;
    float zi = wb.x * x.y + wb.y * x.x + wb.z * x.w + wb.w * x.z;
    float p1 = zr * zr + zi * zi;
    const float4 ta = *(const float4*)&T[i * 8];
    const float4 tb = *(const float4*)&T[i * 8 + 4];
    const float4 tc = *(const float4*)&T1[i * 8];
    const float4 td = *(const float4*)&T1[i * 8 + 4];
    float t0[K_B] = {ta.x, ta.y, ta.z, ta.w, tb.x, tb.y, tb.z, tb.w};
    float t1[K_B] = {tc.x, tc.y, tc.z, tc.w, td.x, td.y, td.z, td.w};
    float R0 = 0.f, R1 = 0.f;
#pragma unroll
    for (int k = 0; k < K_B; ++k) { R0 += t0[k] * vold0[k]; R1 += t1[k] * vold1[k]; }
    float a0 = p0 / (R0 * R0), b0 = 1.0f / R0;
    float a1 = p1 / (R1 * R1), b1 = 1.0f / R1;
#pragma unroll
    for (int k = 0; k < K_B; ++k) {
      num0[k] += a0 * t0[k]; den0[k] += b0 * t0[k];
      num1[k] += a1 * t1[k]; den1[k] += b1 * t1[k];
    }
  }
  __shared__ float red[4][32];
  const int lane = tid & 63, wid = tid >> 6;
#pragma unroll
  for (int k = 0; k < K_B; ++k) {
    float a0 = num0[k], b0 = den0[k], a1 = num1[k], b1 = den1[k];
#pragma unroll
    for (int off = 32; off > 0; off >>= 1) {
      a0 += __shfl_xor(a0, off, 64);
      b0 += __shfl_xor(b0, off, 64);
      a1 += __shfl_xor(a1, off, 64);
      b1 += __shfl_xor(b1, off, 64);
    }
    if (lane == 0) {
      red[wid][k] = a0; red[wid][8 + k] = b0;
      red[wid][16 + k] = a1; red[wid][24 + k] = b1;
    }
  }
  __syncthreads();
  if (tid < 32) red[0][tid] = red[0][tid] + red[1][tid] + red[2][tid] + red[3][tid];
  __syncthreads();
  if (tid < 16) {
    int n = tid >> 3, k = tid & 7;
    float nu = red[0][n * 16 + k];
    float de = red[0][n * 16 + 8 + k];
    size_t idx = ((size_t)n * K_B + k) * J_F + j;
    float vo = V[idx];
    V[idx] = fmaxf(vo * sqrtf(nu / de), NMF_EPS);
  }
}

// ==== D + solve: one block per i, threads stride j, reduce, thread0 solves ====
template<int PK>
__global__ __launch_bounds__(256) void k_d_rows(const float4* __restrict__ Xpt,
                                                const float2* __restrict__ X,
                                                const float* __restrict__ T,
                                                const float* __restrict__ V,
                                                float* __restrict__ W) {
  const int i = blockIdx.x;
  const int tid = threadIdx.x;
  float tr0[K_B], tr1[K_B];
#pragma unroll
  for (int k = 0; k < K_B; ++k) {
    tr0[k] = T[(size_t)i * K_B + k];
    tr1[k] = T[((size_t)I_F + i) * K_B + k];
  }
  float acc[8] = {};  // a00,a11,a01r,a01i, b00,b11,b01r,b01i
  for (int j = tid; j < J_F; j += 256) {
    float4 x = load_xt(Xpt, X, PK, i, j);
    float R0 = 0.f, R1 = 0.f;
#pragma unroll
    for (int k = 0; k < K_B; ++k) {
      R0 += tr0[k] * V[(size_t)k * J_F + j];
      R1 += tr1[k] * V[(size_t)(K_B + k) * J_F + j];
    }
    float wv0 = 1.0f / (R0 + IP_EPS);
    float wv1 = 1.0f / (R1 + IP_EPS);
    float p00 = x.x * x.x + x.y * x.y;
    float p11 = x.z * x.z + x.w * x.w;
    float pr = x.x * x.z + x.y * x.w;
    float pi = x.y * x.z - x.x * x.w;
    acc[0] += wv0 * p00; acc[1] += wv0 * p11; acc[2] += wv0 * pr; acc[3] += wv0 * pi;
    acc[4] += wv1 * p00; acc[5] += wv1 * p11; acc[6] += wv1 * pr; acc[7] += wv1 * pi;
  }
  __shared__ float red[4][8];
  const int lane = tid & 63, wid = tid >> 6;
#pragma unroll
  for (int v = 0; v < 8; ++v) {
    float a = acc[v];
#pragma unroll
    for (int off = 32; off > 0; off >>= 1) a += __shfl_xor(a, off, 64);
    if (lane == 0) red[wid][v] = a;
  }
  __syncthreads();
  if (tid < 8) red[0][tid] = red[0][tid] + red[1][tid] + red[2][tid] + red[3][tid];
  __syncthreads();
  if (tid == 0) {
    float4 wa = ((const float4*)W)[i * 2];
    float4 wb = ((const float4*)W)[i * 2 + 1];
    float w00r = wa.x, w00i = wa.y, w01r = wa.z, w01i = wa.w;
    float w10r = wb.x, w10i = wb.y, w11r = wb.z, w11i = wb.w;
    const float invJ = 1.0f / (float)J_F;
#pragma unroll
    for (int n = 0; n < 2; ++n) {
      float d00 = red[0][n * 4 + 0] * invJ + IP_EPS;
      float d11 = red[0][n * 4 + 1] * invJ + IP_EPS;
      float d01r = red[0][n * 4 + 2] * invJ;
      float d01i = red[0][n * 4 + 3] * invJ;
      float A00r = w00r * d00 + (w01r * d01r + w01i * d01i);
      float A00i = w00i * d00 + (w01i * d01r - w01r * d01i);
      float A01r = (w00r * d01r - w00i * d01i) + w01r * d11;
      float A01i = (w00r * d01i + w00i * d01r) + w01i * d11;
      float A10r = w10r * d00 + (w11r * d01r + w11i * d01i);
      float A10i = w10i * d00 + (w11i * d01r - w11r * d01i);
      float A11r = (w10r * d01r - w10i * d01i) + w11r * d11;
      float A11i = (w10r * d01i + w10i * d01r) + w11i * d11;
      float detr = (A00r * A11r - A00i * A11i) - (A01r * A10r - A01i * A10i);
      float deti = (A00r * A11i + A00i * A11r) - (A01r * A10i + A01i * A10r);
      float idet = 1.0f / (detr * detr + deti * deti);
      float n0r, n0i, n1r, n1i;
      if (n == 0) { n0r = A11r; n0i = A11i; n1r = -A10r; n1i = -A10i; }
      else        { n0r = -A01r; n0i = -A01i; n1r = A00r; n1i = A00i; }
      float b0r = (n0r * detr + n0i * deti) * idet;
      float b0i = (n0i * detr - n0r * deti) * idet;
      float b1r = (n1r * detr + n1i * deti) * idet;
      float b1i = (n1i * detr - n1r * deti) * idet;
      float cr = d01r * b1r - d01i * b1i;
      float ci = d01r * b1i + d01i * b1r;
      float quad = d00 * (b0r * b0r + b0i * b0i) + d11 * (b1r * b1r + b1i * b1i)
                 + 2.0f * (b0r * cr + b0i * ci);
      float s = 1.0f / sqrtf(quad + IP_EPS);
      if (n == 0) { w00r = b0r * s; w00i = -b0i * s; w01r = b1r * s; w01i = -b1i * s; }
      else        { w10r = b0r * s; w10i = -b0i * s; w11r = b1r * s; w11i = -b1i * s; }
    }
    ((float4*)W)[i * 2]     = make_float4(w00r, w00i, w01r, w01i);
    ((float4*)W)[i * 2 + 1] = make_float4(w10r, w10i, w11r, w11i);
  }
}

// ---------------- final: out[n][j][i][2] = Y[i,n,j] ----------------
template<int PK>
__global__ __launch_bounds__(256) void k_final(const float4* __restrict__ Xp,
                                               const float2* __restrict__ X,
                                               const float* __restrict__ W,
                                               float2* __restrict__ out) {
  const int i = blockIdx.x * 256 + threadIdx.x;
  if (i >= I_F) return;
  const float4 wa = ((const float4*)W)[i * 2];
  const float4 wb = ((const float4*)W)[i * 2 + 1];
  const int j0 = blockIdx.y * 8;
  const int jend = min(8, J_F - j0);
  for (int jj = 0; jj < jend; ++jj) {
    const int j = j0 + jj;
    float4 x = load_x(Xp, X, PK, (size_t)j, i);
    float y0r = wa.x * x.x - wa.y * x.y + wa.z * x.z - wa.w * x.w;
    float y0i = wa.x * x.y + wa.y * x.x + wa.z * x.w + wa.w * x.z;
    out[(size_t)j * I_F + i] = make_float2(y0r, y0i);
    float y1r = wb.x * x.x - wb.y * x.y + wb.z * x.z - wb.w * x.w;
    float y1i = wb.x * x.y + wb.y * x.x + wb.z * x.w + wb.w * x.z;
    out[(size_t)(J_F + j) * I_F + i] = make_float2(y1r, y1i);
  }
}

extern "C" void kernel_launch(void* const* d_in, const int* in_sizes, int n_in,
                              void* d_out, int out_size, void* d_ws, size_t ws_size,
                              hipStream_t stream) {
  const float2* X = (const float2*)d_in[0];
  const float* T0 = (const float*)d_in[1];
  const float* V0 = (const float*)d_in[2];
  char* ws = (char*)d_ws;
  size_t off = 0;
  auto alloc = [&](size_t bytes) -> void* {
    void* p = ws + off;
    off = (off + bytes + 255) & ~(size_t)255;
    return p;
  };
  float* W = (float*)alloc((size_t)I_F * 8 * 4);
  float* T = (float*)alloc((size_t)2 * I_F * K_B * 4);
  float* V = (float*)alloc((size_t)2 * K_B * J_F * 4);
  const size_t x_sz = (size_t)J_F * I_F * 16;  // 65.6 MB each
  // priority: Xpt (row kernels) first, then Xp (v_update/final)
  float4* Xpt = nullptr;
  float4* Xp = nullptr;
  if (off + x_sz <= ws_size) Xpt = (float4*)alloc(x_sz);
  if (Xpt && off + x_sz <= ws_size) Xp = (float4*)alloc(x_sz);
  const int pkt = Xpt != nullptr, pkj = Xp != nullptr;

  k_init<<<128, 256, 0, stream>>>(T0, V0, T, V, W);
  if (pkt) k_packT<<<dim3(65, 63), 256, 0, stream>>>(X, Xpt);
  if (pkj) k_pack<<<dim3(9, 250), 256, 0, stream>>>(X, Xp);

  if (pkt && pkj) {
    for (int it = 0; it < N_IT; ++it) {
      k_T_rows<1><<<I_F, 256, 0, stream>>>(Xpt, X, W, T, V);
      k_v_update<1><<<J_F, 256, 0, stream>>>(Xp, X, W, T, V);
      k_d_rows<1><<<I_F, 256, 0, stream>>>(Xpt, X, T, V, W);
    }
    k_final<1><<<dim3(9, 250), 256, 0, stream>>>(Xp, X, W, (float2*)d_out);
  } else if (pkt) {
    for (int it = 0; it < N_IT; ++it) {
      k_T_rows<1><<<I_F, 256, 0, stream>>>(Xpt, X, W, T, V);
      k_v_update<0><<<J_F, 256, 0, stream>>>(nullptr, X, W, T, V);
      k_d_rows<1><<<I_F, 256, 0, stream>>>(Xpt, X, T, V, W);
    }
    k_final<0><<<dim3(9, 250), 256, 0, stream>>>(nullptr, X, W, (float2*)d_out);
  } else {
    for (int it = 0; it < N_IT; ++it) {
      k_T_rows<0><<<I_F, 256, 0, stream>>>(nullptr, X, W, T, V);
      k_v_update<0><<<J_F, 256, 0, stream>>>(nullptr, X, W, T, V);
      k_d_rows<0><<<I_F, 256, 0, stream>>>(nullptr, X, T, V, W);
    }
    k_final<0><<<dim3(9, 250), 256, 0, stream>>>(nullptr, X, W, (float2*)d_out);
  }
}